// Round 3
// baseline (7823.350 us; speedup 1.0000x reference)
//
#include <hip/hip_runtime.h>
#include <hip/hip_bf16.h>
#include <cstdint>

#define DD 20
#define HID 30
#define SCAN_T 1024

__device__ __forceinline__ void load20(const float* __restrict__ p, float* r){
  const float4* q = (const float4*)p;
#pragma unroll
  for (int i=0;i<5;i++){ float4 v=q[i]; r[4*i+0]=v.x; r[4*i+1]=v.y; r[4*i+2]=v.z; r[4*i+3]=v.w; }
}

// Precompute W3cat = [w_past, w_now, w_future], AR[r][j] = sum_k rela[r][k]*w1[j][20+k],
// AQ[r][j] = sum_k rela[r][k]*w1[j][40+k]   (AR/AQ rows padded to 32 floats)
__global__ void k_prep(const float* __restrict__ rela, const float* __restrict__ w1,
                       const float* __restrict__ wp, const float* __restrict__ wn,
                       const float* __restrict__ wf,
                       float* __restrict__ W3, float* __restrict__ AR, float* __restrict__ AQ,
                       int nrel){
  int t = blockIdx.x*blockDim.x + threadIdx.x;
  if (t < 3*DD*DD){
    int s = t/(DD*DD), idx = t%(DD*DD);
    W3[t] = (s==0)?wp[idx]:((s==1)?wn[idx]:wf[idx]);
  }
  if (t < nrel*HID){
    int r=t/HID, j=t-r*HID;
    float sr=0.f, sq=0.f;
#pragma unroll
    for (int k=0;k<DD;k++){
      float e = rela[r*DD+k];
      sr += e*w1[j*3*DD + DD + k];
      sq += e*w1[j*3*DD + 2*DD + k];
    }
    AR[r*32+j]=sr; AQ[r*32+j]=sq;
  }
}

// RT[sel][r][t][:] = (rela[r] + time[t]) @ Wsel^T
__global__ void k_rt(const float* __restrict__ rela, const float* __restrict__ timee,
                     const float* __restrict__ W3, float* __restrict__ RT,
                     int nrel, int ntime){
  int row = blockIdx.x*blockDim.x+threadIdx.x;
  int tot = 3*nrel*ntime;
  if (row>=tot) return;
  int per = nrel*ntime;
  int sel = row/per; int rem = row - sel*per; int r = rem/ntime; int t = rem - r*ntime;
  float e[DD], tv[DD];
  load20(rela + (size_t)r*DD, e);
  load20(timee + (size_t)t*DD, tv);
#pragma unroll
  for (int k=0;k<DD;k++) e[k]+=tv[k];
  const float* W = W3 + sel*DD*DD;
  float o[DD];
#pragma unroll
  for (int i=0;i<DD;i++){
    const float4* wr = (const float4*)(W + i*DD);
    float s=0.f;
#pragma unroll
    for (int c=0;c<5;c++){ float4 w=wr[c]; s += e[4*c]*w.x + e[4*c+1]*w.y + e[4*c+2]*w.z + e[4*c+3]*w.w; }
    o[i]=s;
  }
  float4* op=(float4*)(RT + (size_t)row*DD);
#pragma unroll
  for (int c=0;c<5;c++){ float4 v; v.x=o[4*c]; v.y=o[4*c+1]; v.z=o[4*c+2]; v.w=o[4*c+3]; op[c]=v; }
}

// ---- CSR build ----
__global__ void k_hist(const int* __restrict__ dst, int* __restrict__ cnt, int E){
  int e = blockIdx.x*blockDim.x+threadIdx.x;
  if (e<E) atomicAdd(&cnt[dst[e]],1);
}

__global__ void k_scan_part(const int* __restrict__ cnt, int* __restrict__ part, int N, int C){
  int t = blockIdx.x*blockDim.x+threadIdx.x;
  if (t>=SCAN_T) return;
  int lo=t*C; int hi=lo+C; if (hi>N) hi=N; if (lo>N) lo=N;
  int s=0;
  for (int i=lo;i<hi;i++) s+=cnt[i];
  part[t]=s;
}

__global__ void k_scan_top(int* __restrict__ part){
  __shared__ int sm[SCAN_T];
  int t=threadIdx.x;
  sm[t]=part[t]; __syncthreads();
  for (int off=1; off<SCAN_T; off<<=1){
    int v = (t>=off)? sm[t-off] : 0;
    __syncthreads();
    sm[t]+=v;
    __syncthreads();
  }
  part[t] = (t==0)?0:sm[t-1];
}

__global__ void k_scan_write(const int* __restrict__ cnt, const int* __restrict__ part,
                             int* __restrict__ rowptr, int N, int C){
  int t = blockIdx.x*blockDim.x+threadIdx.x;
  if (t>=SCAN_T) return;
  int lo=t*C; int hi=lo+C; if (hi>N) hi=N; if (lo>N) lo=N;
  int run=part[t];
  for (int i=lo;i<hi;i++){ rowptr[i]=run; run+=cnt[i]; }
  if (hi==N) rowptr[N]=run;
}

__global__ void k_scat(const int* __restrict__ src, const int* __restrict__ dst,
                       const int* __restrict__ rel, const int* __restrict__ qrel,
                       const int* __restrict__ rtm,
                       const int* __restrict__ rowptr, int* __restrict__ cur,
                       int4* __restrict__ recs, int E){
  int e = blockIdx.x*blockDim.x+threadIdx.x;
  if (e>=E) return;
  int d = dst[e];
  int pos = rowptr[d] + atomicAdd(&cur[d],1);
  recs[pos] = make_int4(src[e], rel[e], qrel[e], rtm[e]);
}

// ---- gather: one thread per node, accumulate messages from its CSR range ----
template<bool HASH>
__global__ void __launch_bounds__(256) k_gather(
    const int* __restrict__ rowptr, const int4* __restrict__ recs,
    const float* __restrict__ hin, float* __restrict__ hout,
    const float* __restrict__ RT, const float* __restrict__ AR, const float* __restrict__ AQ,
    const float* __restrict__ w1, const float* __restrict__ w2, const float* __restrict__ W3,
    int N, int nrel, int ntime)
{
  __shared__ float sW1h[HID*DD];
  __shared__ float sW2[32];
  __shared__ float sW3[3*DD*DD];
  for (int t=threadIdx.x; t<HID*DD; t+=blockDim.x){ int j=t/DD,k=t-j*DD; sW1h[t]=w1[j*3*DD+k]; }
  if (threadIdx.x<HID) sW2[threadIdx.x]=w2[threadIdx.x];
  for (int t=threadIdx.x; t<3*DD*DD; t+=blockDim.x) sW3[t]=W3[t];
  __syncthreads();
  int n = blockIdx.x*blockDim.x+threadIdx.x;
  if (n>=N) return;
  int start=rowptr[n], end=rowptr[n+1];

  float acc[DD];
#pragma unroll
  for (int i=0;i<DD;i++) acc[i]=0.f;

  for (int j=start; j<end; ++j){
    int4 rc = recs[j];
    int s=rc.x, r=rc.y, q=rc.z, t=rc.w;
    int sel = (t>0)?2:((t==0)?1:0);
    int ta = (t<0)?-t:t;

    float h[DD];
    if (HASH){
      load20(hin+(size_t)s*DD, h);
#pragma unroll
      for (int i=0;i<DD;i++) h[i]=fmaxf(h[i],0.01f*h[i]);   // leaky_relu folded into gather
    }

    float a[HID];
    {
      const float4* ap=(const float4*)(AR+(size_t)r*32);
      const float4* qp=(const float4*)(AQ+(size_t)q*32);
#pragma unroll
      for (int c=0;c<7;c++){
        float4 x=ap[c], y=qp[c];
        a[4*c+0]=x.x+y.x; a[4*c+1]=x.y+y.y; a[4*c+2]=x.z+y.z; a[4*c+3]=x.w+y.w;
      }
      float2 x=*(const float2*)(AR+(size_t)r*32+28);
      float2 y=*(const float2*)(AQ+(size_t)q*32+28);
      a[28]=x.x+y.x; a[29]=x.y+y.y;
    }
    if (HASH){
#pragma unroll
      for (int jj=0;jj<HID;jj++){
        const float4* wr=(const float4*)&sW1h[jj*DD];
        float sum=a[jj];
#pragma unroll
        for (int c=0;c<5;c++){ float4 w=wr[c]; sum += h[4*c]*w.x+h[4*c+1]*w.y+h[4*c+2]*w.z+h[4*c+3]*w.w; }
        a[jj]=sum;
      }
    }
    float z=0.f;
#pragma unroll
    for (int jj=0;jj<HID;jj++) z += fmaxf(a[jj],0.f)*sW2[jj];
    float score = 1.f/(1.f+__expf(-z));

    float tr[DD];
    load20(RT + ((size_t)(sel*nrel+r)*ntime + ta)*DD, tr);
    if (HASH){
      const float* Ws = sW3 + sel*DD*DD;
#pragma unroll
      for (int i=0;i<DD;i++){
        const float4* wr=(const float4*)(Ws+i*DD);
        float sum=tr[i];
#pragma unroll
        for (int c=0;c<5;c++){ float4 w=wr[c]; sum += h[4*c]*w.x+h[4*c+1]*w.y+h[4*c+2]*w.z+h[4*c+3]*w.w; }
        tr[i]=sum;
      }
    }
#pragma unroll
    for (int i=0;i<DD;i++) acc[i] += score*tr[i];
  }

  float4* op=(float4*)(hout + (size_t)n*DD);
#pragma unroll
  for (int c=0;c<5;c++){ float4 v; v.x=acc[4*c]; v.y=acc[4*c+1]; v.z=acc[4*c+2]; v.w=acc[4*c+3]; op[c]=v; }
}

__global__ void k_result(const float* __restrict__ h, const float* __restrict__ wcls,
                         const float* __restrict__ bcls, float* __restrict__ res, int N){
  int i = blockIdx.x*blockDim.x+threadIdx.x;
  if (i>=N) return;
  float acc = bcls[0];
  const float4* q=(const float4*)(h+(size_t)i*DD);
#pragma unroll
  for (int c=0;c<5;c++){
    float4 v=q[c];
    float x0=fmaxf(v.x,0.01f*v.x), x1=fmaxf(v.y,0.01f*v.y);
    float x2=fmaxf(v.z,0.01f*v.z), x3=fmaxf(v.w,0.01f*v.w);
    acc += x0*wcls[4*c]+x1*wcls[4*c+1]+x2*wcls[4*c+2]+x3*wcls[4*c+3];
  }
  res[i]=acc;
}

__global__ void k_scatter(const float* __restrict__ res, const int* __restrict__ nb,
                          const int* __restrict__ ne, const int* __restrict__ nentp,
                          float* __restrict__ out, int N){
  int i=blockIdx.x*blockDim.x+threadIdx.x;
  if (i>=N) return;
  long long stride = nentp[0];
  out[(long long)nb[i]*stride + ne[i]] = res[i];
}

extern "C" void kernel_launch(void* const* d_in, const int* in_sizes, int n_in,
                              void* d_out, int out_size, void* d_ws, size_t ws_size,
                              hipStream_t stream){
  const int*   src =(const int*)d_in[0];
  const int*   dst =(const int*)d_in[1];
  const int*   rel =(const int*)d_in[2];
  const int*   qrel=(const int*)d_in[3];
  const int*   rtm =(const int*)d_in[4];
  const int*   nb  =(const int*)d_in[5];
  const int*   ne  =(const int*)d_in[6];
  const float* rela=(const float*)d_in[7];
  const float* timee=(const float*)d_in[8];
  const float* w1  =(const float*)d_in[9];
  const float* w2  =(const float*)d_in[10];
  const float* wp  =(const float*)d_in[11];
  const float* wn  =(const float*)d_in[12];
  const float* wf  =(const float*)d_in[13];
  const float* wcls=(const float*)d_in[14];
  const float* bcls=(const float*)d_in[15];
  const int*   nentp=(const int*)d_in[17];

  const int Lc=3;
  int LE=in_sizes[0]; int E=LE/Lc;
  int N=in_sizes[5];
  int nrel=in_sizes[7]/DD;
  int ntime=in_sizes[8]/DD;

  auto al=[](size_t x){ return (x+(size_t)255)&~(size_t)255; };
  size_t szBuf=al((size_t)N*DD*4);
  size_t szRT =al((size_t)3*nrel*ntime*DD*4);
  size_t szA  =al((size_t)nrel*32*4);
  size_t szW3 =al((size_t)3*DD*DD*4);
  size_t szRes=al((size_t)N*4);
  size_t szCnt=al((size_t)N*4);
  size_t szRow=al(((size_t)N+1)*4);
  size_t szPart=al((size_t)SCAN_T*4);
  size_t szRecs=al((size_t)E*16);
  size_t need = 2*szBuf+szRT+2*szA+szW3+szRes+szCnt+szRow+szPart+szRecs;

  char* base; float* res;
  if (ws_size>=need){ base=(char*)d_ws; res=nullptr; }
  else { base=(char*)d_out; res=(float*)d_ws; }   // fallback: scratch inside d_out, result in ws
  size_t off=0;
  float* buf0=(float*)(base+off); off+=szBuf;
  float* buf1=(float*)(base+off); off+=szBuf;
  float* RT  =(float*)(base+off); off+=szRT;
  float* AR  =(float*)(base+off); off+=szA;
  float* AQ  =(float*)(base+off); off+=szA;
  float* W3  =(float*)(base+off); off+=szW3;
  int*   cnt =(int*)(base+off);  off+=szCnt;
  int*   rowptr=(int*)(base+off); off+=szRow;
  int*   part=(int*)(base+off);  off+=szPart;
  int4*  recs=(int4*)(base+off); off+=szRecs;
  if (!res){ res=(float*)(base+off); off+=szRes; }

  dim3 blk(256);
  int prepTot = (3*DD*DD > nrel*HID) ? 3*DD*DD : nrel*HID;
  k_prep<<<dim3((prepTot+255)/256),blk,0,stream>>>(rela,w1,wp,wn,wf,W3,AR,AQ,nrel);
  int rtTot=3*nrel*ntime;
  k_rt<<<dim3((rtTot+255)/256),blk,0,stream>>>(rela,timee,W3,RT,nrel,ntime);

  int C=(N+SCAN_T-1)/SCAN_T;
  dim3 egrid((E+255)/256);
  dim3 ngrid((N+255)/256);
  dim3 sgrid(SCAN_T/256);

  for (int l=0; l<Lc; ++l){
    const int* srcl=src+(size_t)l*E;
    const int* dstl=dst+(size_t)l*E;
    const int* rell=rel+(size_t)l*E;
    const int* qrll=qrel+(size_t)l*E;
    const int* rtml=rtm+(size_t)l*E;
    (void)hipMemsetAsync(cnt,0,(size_t)N*4,stream);
    k_hist<<<egrid,blk,0,stream>>>(dstl,cnt,E);
    k_scan_part<<<sgrid,blk,0,stream>>>(cnt,part,N,C);
    k_scan_top<<<dim3(1),dim3(SCAN_T),0,stream>>>(part);
    k_scan_write<<<sgrid,blk,0,stream>>>(cnt,part,rowptr,N,C);
    (void)hipMemsetAsync(cnt,0,(size_t)N*4,stream);
    k_scat<<<egrid,blk,0,stream>>>(srcl,dstl,rell,qrll,rtml,rowptr,cnt,recs,E);
    const float* hin = (l==0)?nullptr:((l==1)?buf0:buf1);
    float* hout = (l==0)?buf0:((l==1)?buf1:buf0);
    if (l==0)
      k_gather<false><<<ngrid,blk,0,stream>>>(rowptr,recs,hin,hout,RT,AR,AQ,w1,w2,W3,N,nrel,ntime);
    else
      k_gather<true><<<ngrid,blk,0,stream>>>(rowptr,recs,hin,hout,RT,AR,AQ,w1,w2,W3,N,nrel,ntime);
  }

  k_result<<<ngrid,blk,0,stream>>>(buf0,wcls,bcls,res,N);
  (void)hipMemsetAsync(d_out,0,(size_t)out_size*sizeof(float),stream);
  k_scatter<<<ngrid,blk,0,stream>>>(res,nb,ne,nentp,(float*)d_out,N);
}

// Round 4
// 1273.560 us; speedup vs baseline: 6.1429x; 6.1429x over previous
//
#include <hip/hip_runtime.h>
#include <hip/hip_bf16.h>
#include <cstdint>

#define DD 20
#define HID 30
#define NB_SCAN 1024

__device__ __forceinline__ void load20(const float* __restrict__ p, float* r){
  const float4* q = (const float4*)p;
#pragma unroll
  for (int i=0;i<5;i++){ float4 v=q[i]; r[4*i+0]=v.x; r[4*i+1]=v.y; r[4*i+2]=v.z; r[4*i+3]=v.w; }
}

__global__ void k_prep(const float* __restrict__ rela, const float* __restrict__ w1,
                       const float* __restrict__ wp, const float* __restrict__ wn,
                       const float* __restrict__ wf,
                       float* __restrict__ W3, float* __restrict__ AR, float* __restrict__ AQ,
                       int nrel){
  int t = blockIdx.x*blockDim.x + threadIdx.x;
  if (t < 3*DD*DD){
    int s = t/(DD*DD), idx = t%(DD*DD);
    W3[t] = (s==0)?wp[idx]:((s==1)?wn[idx]:wf[idx]);
  }
  if (t < nrel*HID){
    int r=t/HID, j=t-r*HID;
    float sr=0.f, sq=0.f;
#pragma unroll
    for (int k=0;k<DD;k++){
      float e = rela[r*DD+k];
      sr += e*w1[j*3*DD + DD + k];
      sq += e*w1[j*3*DD + 2*DD + k];
    }
    AR[r*32+j]=sr; AQ[r*32+j]=sq;
  }
}

__global__ void k_rt(const float* __restrict__ rela, const float* __restrict__ timee,
                     const float* __restrict__ W3, float* __restrict__ RT,
                     int nrel, int ntime){
  int row = blockIdx.x*blockDim.x+threadIdx.x;
  int tot = 3*nrel*ntime;
  if (row>=tot) return;
  int per = nrel*ntime;
  int sel = row/per; int rem = row - sel*per; int r = rem/ntime; int t = rem - r*ntime;
  float e[DD], tv[DD];
  load20(rela + (size_t)r*DD, e);
  load20(timee + (size_t)t*DD, tv);
#pragma unroll
  for (int k=0;k<DD;k++) e[k]+=tv[k];
  const float* W = W3 + sel*DD*DD;
  float o[DD];
#pragma unroll
  for (int i=0;i<DD;i++){
    const float4* wr = (const float4*)(W + i*DD);
    float s=0.f;
#pragma unroll
    for (int c=0;c<5;c++){ float4 w=wr[c]; s += e[4*c]*w.x + e[4*c+1]*w.y + e[4*c+2]*w.z + e[4*c+3]*w.w; }
    o[i]=s;
  }
  float4* op=(float4*)(RT + (size_t)row*DD);
#pragma unroll
  for (int c=0;c<5;c++){ float4 v; v.x=o[4*c]; v.y=o[4*c+1]; v.z=o[4*c+2]; v.w=o[4*c+3]; op[c]=v; }
}

// ---- CSR build: one histogram pass over ALL layers; rank saved so scatter needs no 2nd atomic ----
__global__ void k_hist_all(const int* __restrict__ dst, int* __restrict__ cnt,
                           int* __restrict__ rank, int LE, int E, int N){
  int e = blockIdx.x*blockDim.x+threadIdx.x;
  if (e>=LE) return;
  int l = e/E;
  int d = dst[e];
  rank[e] = atomicAdd(&cnt[(size_t)l*N+d], 1);
}

__global__ void k_scan_part(const int* __restrict__ cnt, int* __restrict__ part, int M, int C){
  __shared__ int sm[256];
  int b=blockIdx.x, t=threadIdx.x;
  int lo=b*C, hi=lo+C; if (hi>M) hi=M; if (lo>M) lo=M;
  int s=0;
  for (int i=lo+t; i<hi; i+=256) s+=cnt[i];
  sm[t]=s; __syncthreads();
  for (int o=128;o>0;o>>=1){ if (t<o) sm[t]+=sm[t+o]; __syncthreads(); }
  if (t==0) part[b]=sm[0];
}

__global__ void k_scan_top(int* __restrict__ part){
  __shared__ int sm[NB_SCAN];
  int t=threadIdx.x;
  int v=part[t]; sm[t]=v; __syncthreads();
  for (int o=1;o<NB_SCAN;o<<=1){
    int u=(t>=o)?sm[t-o]:0; __syncthreads();
    sm[t]+=u; __syncthreads();
  }
  part[t]=sm[t]-v;   // exclusive
}

__global__ void k_scan_write(const int* __restrict__ cnt, const int* __restrict__ part,
                             int* __restrict__ rowptr, int M, int C){
  __shared__ int sm[256];
  int b=blockIdx.x, t=threadIdx.x;
  int lo=b*C, hi=lo+C; if (hi>M) hi=M; if (lo>M) lo=M;
  int run=part[b];
  for (int base=lo; base<hi; base+=256){
    int i=base+t;
    int v=(i<hi)?cnt[i]:0;
    sm[t]=v; __syncthreads();
    for (int o=1;o<256;o<<=1){
      int u=(t>=o)?sm[t-o]:0; __syncthreads();
      sm[t]+=u; __syncthreads();
    }
    if (i<hi) rowptr[i]=run+sm[t]-v;
    int tot=sm[255];
    __syncthreads();
    run+=tot;
  }
  if (hi==M && t==0) rowptr[M]=run;
}

// ---- per-edge message compute, scatter to CSR slot (no atomics) ----
template<bool HASH>
__global__ void __launch_bounds__(256) k_compute(
    const int* __restrict__ src, const int* __restrict__ dst,
    const int* __restrict__ rel, const int* __restrict__ qrel,
    const int* __restrict__ rtm, const int* __restrict__ rank,
    const int* __restrict__ rowptr, int lE,
    const float* __restrict__ hin, float* __restrict__ msg,
    const float* __restrict__ RT, const float* __restrict__ AR, const float* __restrict__ AQ,
    const float* __restrict__ w1, const float* __restrict__ w2, const float* __restrict__ W3,
    int E, int nrel, int ntime)
{
  __shared__ float sW1h[HID*DD];
  __shared__ float sW2[32];
  __shared__ float sW3[3*DD*DD];
  if (HASH){
    for (int t=threadIdx.x; t<HID*DD; t+=blockDim.x){ int j=t/DD,k=t-j*DD; sW1h[t]=w1[j*3*DD+k]; }
    for (int t=threadIdx.x; t<3*DD*DD; t+=blockDim.x) sW3[t]=W3[t];
  }
  if (threadIdx.x<HID) sW2[threadIdx.x]=w2[threadIdx.x];
  __syncthreads();
  int e = blockIdx.x*blockDim.x+threadIdx.x;
  if (e>=E) return;
  int s=src[e], d=dst[e], r=rel[e], q=qrel[e], t=rtm[e];
  int sel = (t>0)?2:((t==0)?1:0);
  int ta = (t<0)?-t:t;

  float h[DD];
  if (HASH){
    load20(hin+(size_t)s*DD, h);
#pragma unroll
    for (int i=0;i<DD;i++) h[i]=fmaxf(h[i],0.01f*h[i]);   // leaky_relu folded into gather
  }

  float a[HID];
  {
    const float4* ap=(const float4*)(AR+(size_t)r*32);
    const float4* qp=(const float4*)(AQ+(size_t)q*32);
#pragma unroll
    for (int c=0;c<7;c++){
      float4 x=ap[c], y=qp[c];
      a[4*c+0]=x.x+y.x; a[4*c+1]=x.y+y.y; a[4*c+2]=x.z+y.z; a[4*c+3]=x.w+y.w;
    }
    float2 x=*(const float2*)(AR+(size_t)r*32+28);
    float2 y=*(const float2*)(AQ+(size_t)q*32+28);
    a[28]=x.x+y.x; a[29]=x.y+y.y;
  }
  if (HASH){
#pragma unroll
    for (int j=0;j<HID;j++){
      const float4* wr=(const float4*)&sW1h[j*DD];
      float sum=a[j];
#pragma unroll
      for (int c=0;c<5;c++){ float4 w=wr[c]; sum += h[4*c]*w.x+h[4*c+1]*w.y+h[4*c+2]*w.z+h[4*c+3]*w.w; }
      a[j]=sum;
    }
  }
  float z=0.f;
#pragma unroll
  for (int j=0;j<HID;j++) z += fmaxf(a[j],0.f)*sW2[j];
  float score = 1.f/(1.f+__expf(-z));

  float tr[DD];
  load20(RT + ((size_t)(sel*nrel+r)*ntime + ta)*DD, tr);
  if (HASH){
    const float* Ws = sW3 + sel*DD*DD;
#pragma unroll
    for (int i=0;i<DD;i++){
      const float4* wr=(const float4*)(Ws+i*DD);
      float sum=tr[i];
#pragma unroll
      for (int c=0;c<5;c++){ float4 w=wr[c]; sum += h[4*c]*w.x+h[4*c+1]*w.y+h[4*c+2]*w.z+h[4*c+3]*w.w; }
      tr[i]=sum;
    }
  }

  int pos = rowptr[d] - lE + rank[e];
  float4* op=(float4*)(msg + (size_t)pos*DD);
#pragma unroll
  for (int c=0;c<5;c++){ float4 v; v.x=score*tr[4*c]; v.y=score*tr[4*c+1]; v.z=score*tr[4*c+2]; v.w=score*tr[4*c+3]; op[c]=v; }
}

// ---- segmented sum over contiguous msg rows; LAST fuses leaky+cls-dot+output scatter ----
template<bool LAST>
__global__ void __launch_bounds__(256) k_reduce(
    const int* __restrict__ rowptr, int lE, const float* __restrict__ msg,
    float* __restrict__ hout, const float* __restrict__ wcls, const float* __restrict__ bcls,
    const int* __restrict__ nb, const int* __restrict__ ne, const int* __restrict__ nentp,
    float* __restrict__ out, int N)
{
  int n = blockIdx.x*blockDim.x+threadIdx.x;
  if (n>=N) return;
  int start=rowptr[n]-lE, end=rowptr[n+1]-lE;
  float acc[DD];
#pragma unroll
  for (int i=0;i<DD;i++) acc[i]=0.f;
  for (int j=start;j<end;++j){
    const float4* q=(const float4*)(msg+(size_t)j*DD);
#pragma unroll
    for (int c=0;c<5;c++){ float4 v=q[c]; acc[4*c]+=v.x; acc[4*c+1]+=v.y; acc[4*c+2]+=v.z; acc[4*c+3]+=v.w; }
  }
  if (!LAST){
    float4* op=(float4*)(hout+(size_t)n*DD);
#pragma unroll
    for (int c=0;c<5;c++){ float4 v; v.x=acc[4*c]; v.y=acc[4*c+1]; v.z=acc[4*c+2]; v.w=acc[4*c+3]; op[c]=v; }
  } else {
    float rsum=bcls[0];
#pragma unroll
    for (int i=0;i<DD;i++){ float x=fmaxf(acc[i],0.01f*acc[i]); rsum += x*wcls[i]; }
    long long stride = nentp[0];
    out[(long long)nb[n]*stride + ne[n]] = rsum;
  }
}

// ================= fallback (round-2 proven atomic path) =================
template<bool HASH>
__global__ void __launch_bounds__(256) k_edge(
    const int* __restrict__ src, const int* __restrict__ dst,
    const int* __restrict__ rel, const int* __restrict__ qrel,
    const int* __restrict__ rtm,
    const float* __restrict__ hin, float* __restrict__ hout,
    const float* __restrict__ RT, const float* __restrict__ AR, const float* __restrict__ AQ,
    const float* __restrict__ w1, const float* __restrict__ w2, const float* __restrict__ W3,
    int E, int nrel, int ntime)
{
  __shared__ float sW1h[HID*DD];
  __shared__ float sW2[32];
  __shared__ float sW3[3*DD*DD];
  for (int t=threadIdx.x; t<HID*DD; t+=blockDim.x){ int j=t/DD,k=t-j*DD; sW1h[t]=w1[j*3*DD+k]; }
  if (threadIdx.x<HID) sW2[threadIdx.x]=w2[threadIdx.x];
  for (int t=threadIdx.x; t<3*DD*DD; t+=blockDim.x) sW3[t]=W3[t];
  __syncthreads();
  int e = blockIdx.x*blockDim.x+threadIdx.x;
  if (e>=E) return;
  int s=src[e], d=dst[e], r=rel[e], q=qrel[e], t=rtm[e];
  int sel = (t>0)?2:((t==0)?1:0);
  int ta = (t<0)?-t:t;
  float h[DD];
  if (HASH){
    load20(hin+(size_t)s*DD, h);
#pragma unroll
    for (int i=0;i<DD;i++) h[i]=fmaxf(h[i],0.01f*h[i]);
  }
  float a[HID];
  {
    const float4* ap=(const float4*)(AR+(size_t)r*32);
    const float4* qp=(const float4*)(AQ+(size_t)q*32);
#pragma unroll
    for (int c=0;c<7;c++){
      float4 x=ap[c], y=qp[c];
      a[4*c+0]=x.x+y.x; a[4*c+1]=x.y+y.y; a[4*c+2]=x.z+y.z; a[4*c+3]=x.w+y.w;
    }
    float2 x=*(const float2*)(AR+(size_t)r*32+28);
    float2 y=*(const float2*)(AQ+(size_t)q*32+28);
    a[28]=x.x+y.x; a[29]=x.y+y.y;
  }
  if (HASH){
#pragma unroll
    for (int j=0;j<HID;j++){
      const float4* wr=(const float4*)&sW1h[j*DD];
      float sum=a[j];
#pragma unroll
      for (int c=0;c<5;c++){ float4 w=wr[c]; sum += h[4*c]*w.x+h[4*c+1]*w.y+h[4*c+2]*w.z+h[4*c+3]*w.w; }
      a[j]=sum;
    }
  }
  float z=0.f;
#pragma unroll
  for (int j=0;j<HID;j++) z += fmaxf(a[j],0.f)*sW2[j];
  float score = 1.f/(1.f+__expf(-z));
  float tr[DD];
  load20(RT + ((size_t)(sel*nrel+r)*ntime + ta)*DD, tr);
  if (HASH){
    const float* Ws = sW3 + sel*DD*DD;
#pragma unroll
    for (int i=0;i<DD;i++){
      const float4* wr=(const float4*)(Ws+i*DD);
      float sum=tr[i];
#pragma unroll
      for (int c=0;c<5;c++){ float4 w=wr[c]; sum += h[4*c]*w.x+h[4*c+1]*w.y+h[4*c+2]*w.z+h[4*c+3]*w.w; }
      tr[i]=sum;
    }
  }
  float* o = hout + (size_t)d*DD;
#pragma unroll
  for (int i=0;i<DD;i++) atomicAdd(o+i, score*tr[i]);
}

__global__ void k_result(const float* __restrict__ h, const float* __restrict__ wcls,
                         const float* __restrict__ bcls, float* __restrict__ res, int N){
  int i = blockIdx.x*blockDim.x+threadIdx.x;
  if (i>=N) return;
  float acc = bcls[0];
  const float4* q=(const float4*)(h+(size_t)i*DD);
#pragma unroll
  for (int c=0;c<5;c++){
    float4 v=q[c];
    float x0=fmaxf(v.x,0.01f*v.x), x1=fmaxf(v.y,0.01f*v.y);
    float x2=fmaxf(v.z,0.01f*v.z), x3=fmaxf(v.w,0.01f*v.w);
    acc += x0*wcls[4*c]+x1*wcls[4*c+1]+x2*wcls[4*c+2]+x3*wcls[4*c+3];
  }
  res[i]=acc;
}

__global__ void k_scatter(const float* __restrict__ res, const int* __restrict__ nb,
                          const int* __restrict__ ne, const int* __restrict__ nentp,
                          float* __restrict__ out, int N){
  int i=blockIdx.x*blockDim.x+threadIdx.x;
  if (i>=N) return;
  long long stride = nentp[0];
  out[(long long)nb[i]*stride + ne[i]] = res[i];
}

extern "C" void kernel_launch(void* const* d_in, const int* in_sizes, int n_in,
                              void* d_out, int out_size, void* d_ws, size_t ws_size,
                              hipStream_t stream){
  const int*   src =(const int*)d_in[0];
  const int*   dst =(const int*)d_in[1];
  const int*   rel =(const int*)d_in[2];
  const int*   qrel=(const int*)d_in[3];
  const int*   rtm =(const int*)d_in[4];
  const int*   nb  =(const int*)d_in[5];
  const int*   ne  =(const int*)d_in[6];
  const float* rela=(const float*)d_in[7];
  const float* timee=(const float*)d_in[8];
  const float* w1  =(const float*)d_in[9];
  const float* w2  =(const float*)d_in[10];
  const float* wp  =(const float*)d_in[11];
  const float* wn  =(const float*)d_in[12];
  const float* wf  =(const float*)d_in[13];
  const float* wcls=(const float*)d_in[14];
  const float* bcls=(const float*)d_in[15];
  const int*   nentp=(const int*)d_in[17];

  const int Lc=3;
  int LE=in_sizes[0]; int E=LE/Lc;
  int N=in_sizes[5];
  int nrel=in_sizes[7]/DD;
  int ntime=in_sizes[8]/DD;
  int M = Lc*N;

  auto al=[](size_t x){ return (x+(size_t)255)&~(size_t)255; };
  size_t szBuf =al((size_t)N*DD*4);
  size_t szRT  =al((size_t)3*nrel*ntime*DD*4);
  size_t szA   =al((size_t)nrel*32*4);
  size_t szW3  =al((size_t)3*DD*DD*4);
  size_t szRow =al(((size_t)M+1)*4);
  size_t szRank=al((size_t)LE*4);
  size_t szMsg =al((size_t)E*DD*4);          // cnt[M] (12MB) overlays msg (160MB)
  size_t szPart=al((size_t)NB_SCAN*4);
  size_t need = 2*szBuf+szRT+2*szA+szW3+szRow+szRank+szMsg+szPart;

  dim3 blk(256);
  int prepTot = (3*DD*DD > nrel*HID) ? 3*DD*DD : nrel*HID;
  int rtTot=3*nrel*ntime;

  if (ws_size >= need){
    char* base=(char*)d_ws;
    size_t off=0;
    float* buf0=(float*)(base+off); off+=szBuf;
    float* buf1=(float*)(base+off); off+=szBuf;
    float* RT  =(float*)(base+off); off+=szRT;
    float* AR  =(float*)(base+off); off+=szA;
    float* AQ  =(float*)(base+off); off+=szA;
    float* W3  =(float*)(base+off); off+=szW3;
    int*   rowptr=(int*)(base+off); off+=szRow;
    int*   rank=(int*)(base+off);  off+=szRank;
    float* msg =(float*)(base+off); off+=szMsg;
    int*   cnt =(int*)msg;                      // overlay: cnt dead before first msg write
    int*   part=(int*)(base+off);  off+=szPart;

    k_prep<<<dim3((prepTot+255)/256),blk,0,stream>>>(rela,w1,wp,wn,wf,W3,AR,AQ,nrel);
    k_rt<<<dim3((rtTot+255)/256),blk,0,stream>>>(rela,timee,W3,RT,nrel,ntime);

    (void)hipMemsetAsync(cnt,0,(size_t)M*4,stream);
    k_hist_all<<<dim3((LE+255)/256),blk,0,stream>>>(dst,cnt,rank,LE,E,N);
    int C=(M+NB_SCAN-1)/NB_SCAN;
    k_scan_part<<<dim3(NB_SCAN),blk,0,stream>>>(cnt,part,M,C);
    k_scan_top<<<dim3(1),dim3(NB_SCAN),0,stream>>>(part);
    k_scan_write<<<dim3(NB_SCAN),blk,0,stream>>>(cnt,part,rowptr,M,C);

    (void)hipMemsetAsync(d_out,0,(size_t)out_size*sizeof(float),stream);

    dim3 egrid((E+255)/256);
    dim3 ngrid((N+255)/256);
    for (int l=0;l<Lc;++l){
      size_t eo=(size_t)l*E;
      int lE=l*E;
      const float* hin = (l==0)?nullptr:((l==1)?buf0:buf1);
      float* hout = (l==0)?buf0:buf1;           // L2's reduce writes d_out instead
      if (l==0)
        k_compute<false><<<egrid,blk,0,stream>>>(src+eo,dst+eo,rel+eo,qrel+eo,rtm+eo,
            rank+eo,rowptr+(size_t)l*N,lE,hin,msg,RT,AR,AQ,w1,w2,W3,E,nrel,ntime);
      else
        k_compute<true><<<egrid,blk,0,stream>>>(src+eo,dst+eo,rel+eo,qrel+eo,rtm+eo,
            rank+eo,rowptr+(size_t)l*N,lE,hin,msg,RT,AR,AQ,w1,w2,W3,E,nrel,ntime);
      if (l<Lc-1)
        k_reduce<false><<<ngrid,blk,0,stream>>>(rowptr+(size_t)l*N,lE,msg,hout,
            wcls,bcls,nb,ne,nentp,(float*)d_out,N);
      else
        k_reduce<true><<<ngrid,blk,0,stream>>>(rowptr+(size_t)l*N,lE,msg,hout,
            wcls,bcls,nb,ne,nentp,(float*)d_out,N);
    }
  } else {
    // fallback: proven round-2 atomic path (scratch carved from d_out, res in ws)
    size_t szRes=al((size_t)N*4);
    char* base=(char*)d_out; float* res=(float*)d_ws;
    size_t off=0;
    float* buf0=(float*)(base+off); off+=szBuf;
    float* buf1=(float*)(base+off); off+=szBuf;
    float* RT  =(float*)(base+off); off+=szRT;
    float* AR  =(float*)(base+off); off+=szA;
    float* AQ  =(float*)(base+off); off+=szA;
    float* W3  =(float*)(base+off); off+=szW3;
    (void)szRes;
    k_prep<<<dim3((prepTot+255)/256),blk,0,stream>>>(rela,w1,wp,wn,wf,W3,AR,AQ,nrel);
    k_rt<<<dim3((rtTot+255)/256),blk,0,stream>>>(rela,timee,W3,RT,nrel,ntime);
    dim3 egrid((E+255)/256);
    dim3 ngrid((N+255)/256);
    (void)hipMemsetAsync(buf0,0,(size_t)N*DD*4,stream);
    k_edge<false><<<egrid,blk,0,stream>>>(src,dst,rel,qrel,rtm,nullptr,buf0,RT,AR,AQ,w1,w2,W3,E,nrel,ntime);
    (void)hipMemsetAsync(buf1,0,(size_t)N*DD*4,stream);
    k_edge<true><<<egrid,blk,0,stream>>>(src+(size_t)E,dst+(size_t)E,rel+(size_t)E,qrel+(size_t)E,rtm+(size_t)E,
                                         buf0,buf1,RT,AR,AQ,w1,w2,W3,E,nrel,ntime);
    (void)hipMemsetAsync(buf0,0,(size_t)N*DD*4,stream);
    k_edge<true><<<egrid,blk,0,stream>>>(src+(size_t)2*E,dst+(size_t)2*E,rel+(size_t)2*E,qrel+(size_t)2*E,rtm+(size_t)2*E,
                                         buf1,buf0,RT,AR,AQ,w1,w2,W3,E,nrel,ntime);
    k_result<<<ngrid,blk,0,stream>>>(buf0,wcls,bcls,res,N);
    (void)hipMemsetAsync(d_out,0,(size_t)out_size*sizeof(float),stream);
    k_scatter<<<ngrid,blk,0,stream>>>(res,nb,ne,nentp,(float*)d_out,N);
  }
}

// Round 5
// 1149.435 us; speedup vs baseline: 6.8063x; 1.1080x over previous
//
#include <hip/hip_runtime.h>
#include <hip/hip_bf16.h>
#include <cstdint>

#define DD 20
#define HID 30
#define NB_SCAN 1024
#define MROW 21   // LDS msg row stride (coprime with 32 banks)

__device__ __forceinline__ void load20(const float* __restrict__ p, float* r){
  const float4* q = (const float4*)p;
#pragma unroll
  for (int i=0;i<5;i++){ float4 v=q[i]; r[4*i+0]=v.x; r[4*i+1]=v.y; r[4*i+2]=v.z; r[4*i+3]=v.w; }
}

__global__ void k_prep(const float* __restrict__ rela, const float* __restrict__ w1,
                       const float* __restrict__ wp, const float* __restrict__ wn,
                       const float* __restrict__ wf,
                       float* __restrict__ W3, float* __restrict__ AR, float* __restrict__ AQ,
                       int nrel){
  int t = blockIdx.x*blockDim.x + threadIdx.x;
  if (t < 3*DD*DD){
    int s = t/(DD*DD), idx = t%(DD*DD);
    W3[t] = (s==0)?wp[idx]:((s==1)?wn[idx]:wf[idx]);
  }
  if (t < nrel*HID){
    int r=t/HID, j=t-r*HID;
    float sr=0.f, sq=0.f;
#pragma unroll
    for (int k=0;k<DD;k++){
      float e = rela[r*DD+k];
      sr += e*w1[j*3*DD + DD + k];
      sq += e*w1[j*3*DD + 2*DD + k];
    }
    AR[r*32+j]=sr; AQ[r*32+j]=sq;
  }
}

__global__ void k_rt(const float* __restrict__ rela, const float* __restrict__ timee,
                     const float* __restrict__ W3, float* __restrict__ RT,
                     int nrel, int ntime){
  int row = blockIdx.x*blockDim.x+threadIdx.x;
  int tot = 3*nrel*ntime;
  if (row>=tot) return;
  int per = nrel*ntime;
  int sel = row/per; int rem = row - sel*per; int r = rem/ntime; int t = rem - r*ntime;
  float e[DD], tv[DD];
  load20(rela + (size_t)r*DD, e);
  load20(timee + (size_t)t*DD, tv);
#pragma unroll
  for (int k=0;k<DD;k++) e[k]+=tv[k];
  const float* W = W3 + sel*DD*DD;
  float o[DD];
#pragma unroll
  for (int i=0;i<DD;i++){
    const float4* wr = (const float4*)(W + i*DD);
    float s=0.f;
#pragma unroll
    for (int c=0;c<5;c++){ float4 w=wr[c]; s += e[4*c]*w.x + e[4*c+1]*w.y + e[4*c+2]*w.z + e[4*c+3]*w.w; }
    o[i]=s;
  }
  float4* op=(float4*)(RT + (size_t)row*DD);
#pragma unroll
  for (int c=0;c<5;c++){ float4 v; v.x=o[4*c]; v.y=o[4*c+1]; v.z=o[4*c+2]; v.w=o[4*c+3]; op[c]=v; }
}

// ---- CSR build ----
__global__ void k_hist_all(const int* __restrict__ dst, int* __restrict__ cnt,
                           int* __restrict__ rank, int LE, int E, int N){
  int e = blockIdx.x*blockDim.x+threadIdx.x;
  if (e>=LE) return;
  int l = e/E;
  int d = dst[e];
  rank[e] = atomicAdd(&cnt[(size_t)l*N+d], 1);
}

__global__ void k_scan_part(const int* __restrict__ cnt, int* __restrict__ part, int M, int C){
  __shared__ int sm[256];
  int b=blockIdx.x, t=threadIdx.x;
  int lo=b*C, hi=lo+C; if (hi>M) hi=M; if (lo>M) lo=M;
  int s=0;
  for (int i=lo+t; i<hi; i+=256) s+=cnt[i];
  sm[t]=s; __syncthreads();
  for (int o=128;o>0;o>>=1){ if (t<o) sm[t]+=sm[t+o]; __syncthreads(); }
  if (t==0) part[b]=sm[0];
}

__global__ void k_scan_top(int* __restrict__ part){
  __shared__ int sm[NB_SCAN];
  int t=threadIdx.x;
  int v=part[t]; sm[t]=v; __syncthreads();
  for (int o=1;o<NB_SCAN;o<<=1){
    int u=(t>=o)?sm[t-o]:0; __syncthreads();
    sm[t]+=u; __syncthreads();
  }
  part[t]=sm[t]-v;   // exclusive
}

__global__ void k_scan_write(const int* __restrict__ cnt, const int* __restrict__ part,
                             int* __restrict__ rowptr, int M, int C){
  __shared__ int sm[256];
  int b=blockIdx.x, t=threadIdx.x;
  int lo=b*C, hi=lo+C; if (hi>M) hi=M; if (lo>M) lo=M;
  int run=part[b];
  for (int base=lo; base<hi; base+=256){
    int i=base+t;
    int v=(i<hi)?cnt[i]:0;
    sm[t]=v; __syncthreads();
    for (int o=1;o<256;o<<=1){
      int u=(t>=o)?sm[t-o]:0; __syncthreads();
      sm[t]+=u; __syncthreads();
    }
    if (i<hi) rowptr[i]=run+sm[t]-v;
    int tot=sm[255];
    __syncthreads();
    run+=tot;
  }
  if (hi==M && t==0) rowptr[M]=run;
}

// reorder edge fields into CSR order: recs[pos] = {src, rel|qrel<<16, rtm, dst}
__global__ void k_scat_all(const int* __restrict__ src, const int* __restrict__ dst,
                           const int* __restrict__ rel, const int* __restrict__ qrel,
                           const int* __restrict__ rtm,
                           const int* __restrict__ rank, const int* __restrict__ rowptr,
                           int4* __restrict__ recs, int LE, int E, int N){
  int e = blockIdx.x*blockDim.x+threadIdx.x;
  if (e>=LE) return;
  int l = e/E;
  int d = dst[e];
  int pos = rowptr[(size_t)l*N+d] + rank[e];
  recs[pos] = make_int4(src[e], rel[e] | (qrel[e]<<16), rtm[e], d);
}

// ---- fused per-edge compute + LDS segmented reduction ----
template<bool HASH>
__global__ void __launch_bounds__(256) k_layer(
    const int4* __restrict__ recs,            // already offset by l*E
    const float* __restrict__ hin, float* __restrict__ hout,   // hout pre-zeroed
    const float* __restrict__ RT, const float* __restrict__ AR, const float* __restrict__ AQ,
    const float* __restrict__ w1, const float* __restrict__ w2, const float* __restrict__ W3,
    int E, int nrel, int ntime)
{
  __shared__ float sW1h[HID*DD];
  __shared__ float sW2[32];
  __shared__ float sW3[3*DD*DD];
  __shared__ float smsg[256*MROW];
  __shared__ int   sdst[256];
  __shared__ int   s_prevdst, s_nextdst;
  if (HASH){
    for (int t=threadIdx.x; t<HID*DD; t+=blockDim.x){ int j=t/DD,k=t-j*DD; sW1h[t]=w1[j*3*DD+k]; }
    for (int t=threadIdx.x; t<3*DD*DD; t+=blockDim.x) sW3[t]=W3[t];
  }
  if (threadIdx.x<HID) sW2[threadIdx.x]=w2[threadIdx.x];

  int tid = threadIdx.x;
  int bstart = blockIdx.x*256;
  int bsize = E - bstart; if (bsize>256) bsize=256;
  int j = bstart + tid;
  bool active = (tid < bsize);

  if (tid==0){
    s_prevdst = (bstart>0) ? recs[-1 + (ptrdiff_t)bstart].w : -1;
    s_nextdst = (bstart+bsize < E) ? recs[bstart+bsize].w : -1;
  }

  int dstv = -1;
  float m[DD];
  if (active){
    int4 rc = recs[j];
    int s = rc.x;
    int r = rc.y & 0xFFFF;
    int q = ((unsigned)rc.y) >> 16;
    int t = rc.z;
    dstv  = rc.w;
    int sel = (t>0)?2:((t==0)?1:0);
    int ta = (t<0)?-t:t;

    float h[DD];
    if (HASH){
      load20(hin+(size_t)s*DD, h);
#pragma unroll
      for (int i=0;i<DD;i++) h[i]=fmaxf(h[i],0.01f*h[i]);   // leaky folded into gather
    }

    float a[HID];
    {
      const float4* ap=(const float4*)(AR+(size_t)r*32);
      const float4* qp=(const float4*)(AQ+(size_t)q*32);
#pragma unroll
      for (int c=0;c<7;c++){
        float4 x=ap[c], y=qp[c];
        a[4*c+0]=x.x+y.x; a[4*c+1]=x.y+y.y; a[4*c+2]=x.z+y.z; a[4*c+3]=x.w+y.w;
      }
      float2 x=*(const float2*)(AR+(size_t)r*32+28);
      float2 y=*(const float2*)(AQ+(size_t)q*32+28);
      a[28]=x.x+y.x; a[29]=x.y+y.y;
    }
    if (HASH){
#pragma unroll
      for (int jj=0;jj<HID;jj++){
        const float4* wr=(const float4*)&sW1h[jj*DD];
        float sum=a[jj];
#pragma unroll
        for (int c=0;c<5;c++){ float4 w=wr[c]; sum += h[4*c]*w.x+h[4*c+1]*w.y+h[4*c+2]*w.z+h[4*c+3]*w.w; }
        a[jj]=sum;
      }
    }
    float z=0.f;
#pragma unroll
    for (int jj=0;jj<HID;jj++) z += fmaxf(a[jj],0.f)*sW2[jj];
    float score = 1.f/(1.f+__expf(-z));

    float tr[DD];
    load20(RT + ((size_t)(sel*nrel+r)*ntime + ta)*DD, tr);
    if (HASH){
      const float* Ws = sW3 + sel*DD*DD;
#pragma unroll
      for (int i=0;i<DD;i++){
        const float4* wr=(const float4*)(Ws+i*DD);
        float sum=tr[i];
#pragma unroll
        for (int c=0;c<5;c++){ float4 w=wr[c]; sum += h[4*c]*w.x+h[4*c+1]*w.y+h[4*c+2]*w.z+h[4*c+3]*w.w; }
        tr[i]=sum;
      }
    }
#pragma unroll
    for (int i=0;i<DD;i++){ m[i]=score*tr[i]; smsg[tid*MROW+i]=m[i]; }
  }
  sdst[tid] = active ? dstv : -2;
  __syncthreads();

  if (active){
    bool isHead = (tid==0) ? (s_prevdst != dstv) : (sdst[tid-1] != dstv);
    if (isHead || tid==0){
      int k=tid+1;
      for (; k<bsize && sdst[k]==dstv; ++k){
        const float* row=&smsg[k*MROW];
#pragma unroll
        for (int i=0;i<DD;i++) m[i]+=row[i];
      }
      bool crossStart = (tid==0 && !isHead);
      bool crossEnd   = (k==bsize) && (s_nextdst==dstv);
      float* o = hout + (size_t)dstv*DD;
      if (crossStart || crossEnd){
#pragma unroll
        for (int i=0;i<DD;i++) atomicAdd(o+i, m[i]);
      } else {
        float4* op=(float4*)o;
#pragma unroll
        for (int c=0;c<5;c++){ float4 v; v.x=m[4*c]; v.y=m[4*c+1]; v.z=m[4*c+2]; v.w=m[4*c+3]; op[c]=v; }
      }
    }
  }
}

// ---- final: leaky + cls dot + scatter to output ----
__global__ void k_final(const float* __restrict__ h, const float* __restrict__ wcls,
                        const float* __restrict__ bcls, const int* __restrict__ nb,
                        const int* __restrict__ ne, const int* __restrict__ nentp,
                        float* __restrict__ out, int N){
  int n = blockIdx.x*blockDim.x+threadIdx.x;
  if (n>=N) return;
  float acc = bcls[0];
  const float4* q=(const float4*)(h+(size_t)n*DD);
#pragma unroll
  for (int c=0;c<5;c++){
    float4 v=q[c];
    float x0=fmaxf(v.x,0.01f*v.x), x1=fmaxf(v.y,0.01f*v.y);
    float x2=fmaxf(v.z,0.01f*v.z), x3=fmaxf(v.w,0.01f*v.w);
    acc += x0*wcls[4*c]+x1*wcls[4*c+1]+x2*wcls[4*c+2]+x3*wcls[4*c+3];
  }
  long long stride = nentp[0];
  out[(long long)nb[n]*stride + ne[n]] = acc;
}

// ================= fallback (round-2 proven atomic path) =================
template<bool HASH>
__global__ void __launch_bounds__(256) k_edge(
    const int* __restrict__ src, const int* __restrict__ dst,
    const int* __restrict__ rel, const int* __restrict__ qrel,
    const int* __restrict__ rtm,
    const float* __restrict__ hin, float* __restrict__ hout,
    const float* __restrict__ RT, const float* __restrict__ AR, const float* __restrict__ AQ,
    const float* __restrict__ w1, const float* __restrict__ w2, const float* __restrict__ W3,
    int E, int nrel, int ntime)
{
  __shared__ float sW1h[HID*DD];
  __shared__ float sW2[32];
  __shared__ float sW3[3*DD*DD];
  for (int t=threadIdx.x; t<HID*DD; t+=blockDim.x){ int j=t/DD,k=t-j*DD; sW1h[t]=w1[j*3*DD+k]; }
  if (threadIdx.x<HID) sW2[threadIdx.x]=w2[threadIdx.x];
  for (int t=threadIdx.x; t<3*DD*DD; t+=blockDim.x) sW3[t]=W3[t];
  __syncthreads();
  int e = blockIdx.x*blockDim.x+threadIdx.x;
  if (e>=E) return;
  int s=src[e], d=dst[e], r=rel[e], q=qrel[e], t=rtm[e];
  int sel = (t>0)?2:((t==0)?1:0);
  int ta = (t<0)?-t:t;
  float h[DD];
  if (HASH){
    load20(hin+(size_t)s*DD, h);
#pragma unroll
    for (int i=0;i<DD;i++) h[i]=fmaxf(h[i],0.01f*h[i]);
  }
  float a[HID];
  {
    const float4* ap=(const float4*)(AR+(size_t)r*32);
    const float4* qp=(const float4*)(AQ+(size_t)q*32);
#pragma unroll
    for (int c=0;c<7;c++){
      float4 x=ap[c], y=qp[c];
      a[4*c+0]=x.x+y.x; a[4*c+1]=x.y+y.y; a[4*c+2]=x.z+y.z; a[4*c+3]=x.w+y.w;
    }
    float2 x=*(const float2*)(AR+(size_t)r*32+28);
    float2 y=*(const float2*)(AQ+(size_t)q*32+28);
    a[28]=x.x+y.x; a[29]=x.y+y.y;
  }
  if (HASH){
#pragma unroll
    for (int j=0;j<HID;j++){
      const float4* wr=(const float4*)&sW1h[j*DD];
      float sum=a[j];
#pragma unroll
      for (int c=0;c<5;c++){ float4 w=wr[c]; sum += h[4*c]*w.x+h[4*c+1]*w.y+h[4*c+2]*w.z+h[4*c+3]*w.w; }
      a[j]=sum;
    }
  }
  float z=0.f;
#pragma unroll
  for (int j=0;j<HID;j++) z += fmaxf(a[j],0.f)*sW2[j];
  float score = 1.f/(1.f+__expf(-z));
  float tr[DD];
  load20(RT + ((size_t)(sel*nrel+r)*ntime + ta)*DD, tr);
  if (HASH){
    const float* Ws = sW3 + sel*DD*DD;
#pragma unroll
    for (int i=0;i<DD;i++){
      const float4* wr=(const float4*)(Ws+i*DD);
      float sum=tr[i];
#pragma unroll
      for (int c=0;c<5;c++){ float4 w=wr[c]; sum += h[4*c]*w.x+h[4*c+1]*w.y+h[4*c+2]*w.z+h[4*c+3]*w.w; }
      tr[i]=sum;
    }
  }
  float* o = hout + (size_t)d*DD;
#pragma unroll
  for (int i=0;i<DD;i++) atomicAdd(o+i, score*tr[i]);
}

__global__ void k_result(const float* __restrict__ h, const float* __restrict__ wcls,
                         const float* __restrict__ bcls, float* __restrict__ res, int N){
  int i = blockIdx.x*blockDim.x+threadIdx.x;
  if (i>=N) return;
  float acc = bcls[0];
  const float4* q=(const float4*)(h+(size_t)i*DD);
#pragma unroll
  for (int c=0;c<5;c++){
    float4 v=q[c];
    float x0=fmaxf(v.x,0.01f*v.x), x1=fmaxf(v.y,0.01f*v.y);
    float x2=fmaxf(v.z,0.01f*v.z), x3=fmaxf(v.w,0.01f*v.w);
    acc += x0*wcls[4*c]+x1*wcls[4*c+1]+x2*wcls[4*c+2]+x3*wcls[4*c+3];
  }
  res[i]=acc;
}

__global__ void k_scatter(const float* __restrict__ res, const int* __restrict__ nb,
                          const int* __restrict__ ne, const int* __restrict__ nentp,
                          float* __restrict__ out, int N){
  int i=blockIdx.x*blockDim.x+threadIdx.x;
  if (i>=N) return;
  long long stride = nentp[0];
  out[(long long)nb[i]*stride + ne[i]] = res[i];
}

extern "C" void kernel_launch(void* const* d_in, const int* in_sizes, int n_in,
                              void* d_out, int out_size, void* d_ws, size_t ws_size,
                              hipStream_t stream){
  const int*   src =(const int*)d_in[0];
  const int*   dst =(const int*)d_in[1];
  const int*   rel =(const int*)d_in[2];
  const int*   qrel=(const int*)d_in[3];
  const int*   rtm =(const int*)d_in[4];
  const int*   nb  =(const int*)d_in[5];
  const int*   ne  =(const int*)d_in[6];
  const float* rela=(const float*)d_in[7];
  const float* timee=(const float*)d_in[8];
  const float* w1  =(const float*)d_in[9];
  const float* w2  =(const float*)d_in[10];
  const float* wp  =(const float*)d_in[11];
  const float* wn  =(const float*)d_in[12];
  const float* wf  =(const float*)d_in[13];
  const float* wcls=(const float*)d_in[14];
  const float* bcls=(const float*)d_in[15];
  const int*   nentp=(const int*)d_in[17];

  const int Lc=3;
  int LE=in_sizes[0]; int E=LE/Lc;
  int N=in_sizes[5];
  int nrel=in_sizes[7]/DD;
  int ntime=in_sizes[8]/DD;
  int M = Lc*N;

  auto al=[](size_t x){ return (x+(size_t)255)&~(size_t)255; };
  size_t szBuf =al((size_t)N*DD*4);
  size_t szRT  =al((size_t)3*nrel*ntime*DD*4);
  size_t szA   =al((size_t)nrel*32*4);
  size_t szW3  =al((size_t)3*DD*DD*4);
  size_t szRow =al(((size_t)M+1)*4);
  size_t szRank=al((size_t)LE*4);
  size_t szCnt =al((size_t)M*4);
  size_t szRecs=al((size_t)LE*16);
  size_t szPart=al((size_t)NB_SCAN*4);
  size_t need = 2*szBuf+szRT+2*szA+szW3+szRow+szRank+szCnt+szRecs+szPart;

  dim3 blk(256);
  int prepTot = (3*DD*DD > nrel*HID) ? 3*DD*DD : nrel*HID;
  int rtTot=3*nrel*ntime;

  if (ws_size >= need){
    char* base=(char*)d_ws;
    size_t off=0;
    float* buf0=(float*)(base+off); off+=szBuf;
    float* buf1=(float*)(base+off); off+=szBuf;
    float* RT  =(float*)(base+off); off+=szRT;
    float* AR  =(float*)(base+off); off+=szA;
    float* AQ  =(float*)(base+off); off+=szA;
    float* W3  =(float*)(base+off); off+=szW3;
    int*   rowptr=(int*)(base+off); off+=szRow;
    int*   rank=(int*)(base+off);  off+=szRank;
    int*   cnt =(int*)(base+off);  off+=szCnt;
    int4*  recs=(int4*)(base+off); off+=szRecs;
    int*   part=(int*)(base+off);  off+=szPart;

    k_prep<<<dim3((prepTot+255)/256),blk,0,stream>>>(rela,w1,wp,wn,wf,W3,AR,AQ,nrel);
    k_rt<<<dim3((rtTot+255)/256),blk,0,stream>>>(rela,timee,W3,RT,nrel,ntime);

    (void)hipMemsetAsync(cnt,0,(size_t)M*4,stream);
    k_hist_all<<<dim3((LE+255)/256),blk,0,stream>>>(dst,cnt,rank,LE,E,N);
    int C=(M+NB_SCAN-1)/NB_SCAN;
    k_scan_part<<<dim3(NB_SCAN),blk,0,stream>>>(cnt,part,M,C);
    k_scan_top<<<dim3(1),dim3(NB_SCAN),0,stream>>>(part);
    k_scan_write<<<dim3(NB_SCAN),blk,0,stream>>>(cnt,part,rowptr,M,C);
    k_scat_all<<<dim3((LE+255)/256),blk,0,stream>>>(src,dst,rel,qrel,rtm,rank,rowptr,recs,LE,E,N);

    (void)hipMemsetAsync(d_out,0,(size_t)out_size*sizeof(float),stream);
    (void)hipMemsetAsync(buf0,0,(size_t)N*DD*4,stream);
    (void)hipMemsetAsync(buf1,0,(size_t)N*DD*4,stream);

    dim3 egrid((E+255)/256);
    dim3 ngrid((N+255)/256);
    // layer 0: hidden=0 -> buf0
    k_layer<false><<<egrid,blk,0,stream>>>(recs,nullptr,buf0,RT,AR,AQ,w1,w2,W3,E,nrel,ntime);
    // layer 1: buf0 -> buf1
    k_layer<true><<<egrid,blk,0,stream>>>(recs+(size_t)E,buf0,buf1,RT,AR,AQ,w1,w2,W3,E,nrel,ntime);
    // layer 2: buf1 -> buf0 (re-zero buf0 first; stream order makes this safe)
    (void)hipMemsetAsync(buf0,0,(size_t)N*DD*4,stream);
    k_layer<true><<<egrid,blk,0,stream>>>(recs+(size_t)2*E,buf1,buf0,RT,AR,AQ,w1,w2,W3,E,nrel,ntime);

    k_final<<<ngrid,blk,0,stream>>>(buf0,wcls,bcls,nb,ne,nentp,(float*)d_out,N);
  } else {
    // fallback: proven round-2 atomic path (scratch carved from d_out, res in ws)
    char* base=(char*)d_out; float* res=(float*)d_ws;
    size_t off=0;
    float* buf0=(float*)(base+off); off+=szBuf;
    float* buf1=(float*)(base+off); off+=szBuf;
    float* RT  =(float*)(base+off); off+=szRT;
    float* AR  =(float*)(base+off); off+=szA;
    float* AQ  =(float*)(base+off); off+=szA;
    float* W3  =(float*)(base+off); off+=szW3;
    k_prep<<<dim3((prepTot+255)/256),blk,0,stream>>>(rela,w1,wp,wn,wf,W3,AR,AQ,nrel);
    k_rt<<<dim3((rtTot+255)/256),blk,0,stream>>>(rela,timee,W3,RT,nrel,ntime);
    dim3 egrid((E+255)/256);
    dim3 ngrid((N+255)/256);
    (void)hipMemsetAsync(buf0,0,(size_t)N*DD*4,stream);
    k_edge<false><<<egrid,blk,0,stream>>>(src,dst,rel,qrel,rtm,nullptr,buf0,RT,AR,AQ,w1,w2,W3,E,nrel,ntime);
    (void)hipMemsetAsync(buf1,0,(size_t)N*DD*4,stream);
    k_edge<true><<<egrid,blk,0,stream>>>(src+(size_t)E,dst+(size_t)E,rel+(size_t)E,qrel+(size_t)E,rtm+(size_t)E,
                                         buf0,buf1,RT,AR,AQ,w1,w2,W3,E,nrel,ntime);
    (void)hipMemsetAsync(buf0,0,(size_t)N*DD*4,stream);
    k_edge<true><<<egrid,blk,0,stream>>>(src+(size_t)2*E,dst+(size_t)2*E,rel+(size_t)2*E,qrel+(size_t)2*E,rtm+(size_t)2*E,
                                         buf1,buf0,RT,AR,AQ,w1,w2,W3,E,nrel,ntime);
    k_result<<<ngrid,blk,0,stream>>>(buf0,wcls,bcls,res,N);
    (void)hipMemsetAsync(d_out,0,(size_t)out_size*sizeof(float),stream);
    k_scatter<<<ngrid,blk,0,stream>>>(res,nb,ne,nentp,(float*)d_out,N);
  }
}

// Round 6
// 1122.305 us; speedup vs baseline: 6.9708x; 1.0242x over previous
//
#include <hip/hip_runtime.h>
#include <hip/hip_bf16.h>
#include <cstdint>

#define DD 20
#define HID 30
#define NB_SCAN 1024
#define MROW 21   // LDS msg row stride (coprime with 32 banks)

__device__ __forceinline__ void load20(const float* __restrict__ p, float* r){
  const float4* q = (const float4*)p;
#pragma unroll
  for (int i=0;i<5;i++){ float4 v=q[i]; r[4*i+0]=v.x; r[4*i+1]=v.y; r[4*i+2]=v.z; r[4*i+3]=v.w; }
}

__global__ void k_prep(const float* __restrict__ rela, const float* __restrict__ w1,
                       const float* __restrict__ wp, const float* __restrict__ wn,
                       const float* __restrict__ wf,
                       float* __restrict__ W3, float* __restrict__ AR, float* __restrict__ AQ,
                       int nrel){
  int t = blockIdx.x*blockDim.x + threadIdx.x;
  if (t < 3*DD*DD){
    int s = t/(DD*DD), idx = t%(DD*DD);
    W3[t] = (s==0)?wp[idx]:((s==1)?wn[idx]:wf[idx]);
  }
  if (t < nrel*HID){
    int r=t/HID, j=t-r*HID;
    float sr=0.f, sq=0.f;
#pragma unroll
    for (int k=0;k<DD;k++){
      float e = rela[r*DD+k];
      sr += e*w1[j*3*DD + DD + k];
      sq += e*w1[j*3*DD + 2*DD + k];
    }
    AR[r*32+j]=sr; AQ[r*32+j]=sq;
  }
}

__global__ void k_rt(const float* __restrict__ rela, const float* __restrict__ timee,
                     const float* __restrict__ W3, float* __restrict__ RT,
                     int nrel, int ntime){
  int row = blockIdx.x*blockDim.x+threadIdx.x;
  int tot = 3*nrel*ntime;
  if (row>=tot) return;
  int per = nrel*ntime;
  int sel = row/per; int rem = row - sel*per; int r = rem/ntime; int t = rem - r*ntime;
  float e[DD], tv[DD];
  load20(rela + (size_t)r*DD, e);
  load20(timee + (size_t)t*DD, tv);
#pragma unroll
  for (int k=0;k<DD;k++) e[k]+=tv[k];
  const float* W = W3 + sel*DD*DD;
  float o[DD];
#pragma unroll
  for (int i=0;i<DD;i++){
    const float4* wr = (const float4*)(W + i*DD);
    float s=0.f;
#pragma unroll
    for (int c=0;c<5;c++){ float4 w=wr[c]; s += e[4*c]*w.x + e[4*c+1]*w.y + e[4*c+2]*w.z + e[4*c+3]*w.w; }
    o[i]=s;
  }
  float4* op=(float4*)(RT + (size_t)row*DD);
#pragma unroll
  for (int c=0;c<5;c++){ float4 v; v.x=o[4*c]; v.y=o[4*c+1]; v.z=o[4*c+2]; v.w=o[4*c+3]; op[c]=v; }
}

// ---- F0: zero d_out/buf0/buf1 blocks interleaved with layer-0 histogram blocks ----
__global__ void __launch_bounds__(256) k_pre(const int* __restrict__ dst0, int* __restrict__ cnt0,
        int* __restrict__ rank0, int E,
        float4* __restrict__ dout4, size_t nd4,
        float4* __restrict__ b04, float4* __restrict__ b14, size_t nb4){
  int g=blockIdx.x, tid=threadIdx.x;
  int half=gridDim.x>>1;
  if (g & 1){
    int stride=half*256;
    for (int e=(g>>1)*256+tid; e<E; e+=stride)
      rank0[e]=atomicAdd(&cnt0[dst0[e]],1);
  } else {
    float4 z=make_float4(0.f,0.f,0.f,0.f);
    size_t i=(size_t)(g>>1)*256+tid, st=(size_t)half*256;
    for (size_t k=i;k<nd4;k+=st) dout4[k]=z;
    for (size_t k=i;k<nb4;k+=st){ b04[k]=z; b14[k]=z; }
  }
}

// ---- per-layer scan (N elements) ----
__global__ void k_scan_part(const int* __restrict__ cnt, int* __restrict__ part, int M, int C){
  __shared__ int sm[256];
  int b=blockIdx.x, t=threadIdx.x;
  int lo=b*C, hi=lo+C; if (hi>M) hi=M; if (lo>M) lo=M;
  int s=0;
  for (int i=lo+t; i<hi; i+=256) s+=cnt[i];
  sm[t]=s; __syncthreads();
  for (int o=128;o>0;o>>=1){ if (t<o) sm[t]+=sm[t+o]; __syncthreads(); }
  if (t==0) part[b]=sm[0];
}

__global__ void k_scan_top(int* __restrict__ part){
  __shared__ int sm[NB_SCAN];
  int t=threadIdx.x;
  int v=part[t]; sm[t]=v; __syncthreads();
  for (int o=1;o<NB_SCAN;o<<=1){
    int u=(t>=o)?sm[t-o]:0; __syncthreads();
    sm[t]+=u; __syncthreads();
  }
  part[t]=sm[t]-v;   // exclusive
}

__global__ void k_scan_write(const int* __restrict__ cnt, const int* __restrict__ part,
                             int* __restrict__ rowptr, int M, int C){
  __shared__ int sm[256];
  int b=blockIdx.x, t=threadIdx.x;
  int lo=b*C, hi=lo+C; if (hi>M) hi=M; if (lo>M) lo=M;
  int run=part[b];
  for (int base=lo; base<hi; base+=256){
    int i=base+t;
    int v=(i<hi)?cnt[i]:0;
    sm[t]=v; __syncthreads();
    for (int o=1;o<256;o<<=1){
      int u=(t>=o)?sm[t-o]:0; __syncthreads();
      sm[t]+=u; __syncthreads();
    }
    if (i<hi) rowptr[i]=run+sm[t]-v;
    int tot=sm[255];
    __syncthreads();
    run+=tot;
  }
  if (hi==M && t==0) rowptr[M]=run;
}

// ---- per-layer scatter to CSR slots; optional extra blocks (fill-base / zero-buf) ----
__global__ void __launch_bounds__(256) k_scat(const int* __restrict__ src,const int* __restrict__ dst,
  const int* __restrict__ rel,const int* __restrict__ qrel,const int* __restrict__ rtm,
  const int* __restrict__ rank,const int* __restrict__ rowptr,int4* __restrict__ recs,int E,
  int xb,int mode,
  float* __restrict__ dout,const int* __restrict__ nb,const int* __restrict__ ne,
  const int* __restrict__ nentp,const float* __restrict__ bcls,int N,
  float4* __restrict__ zbuf,size_t nz4,int* __restrict__ listc){
  int g=blockIdx.x, tid=threadIdx.x;
  if (g<xb){
    if (mode==0){
      float b=bcls[0]; long long stride=nentp[0];
      for (int n=g*256+tid;n<N;n+=xb*256) dout[(long long)nb[n]*stride+ne[n]]=b;
    } else {
      if (g==0&&tid==0) *listc=0;
      float4 z=make_float4(0.f,0.f,0.f,0.f);
      for (size_t k=(size_t)g*256+tid;k<nz4;k+=(size_t)xb*256) zbuf[k]=z;
    }
    return;
  }
  int e=(g-xb)*256+tid;
  if (e>=E) return;
  int d=dst[e];
  int pos=rowptr[d]+rank[e];
  recs[pos]=make_int4(src[e], rel[e]|(qrel[e]<<16), rtm[e], d);
}

// ---- fused layer: per-edge compute + LDS segmented reduce, optionally ∥ next-layer hist,
//      optionally fused final epilogue (leaky + cls-dot + scatter to d_out) ----
template<bool HASH,bool HIST,bool FINAL>
__global__ void __launch_bounds__(256) k_fused(
    const int4* __restrict__ recs,
    const float* __restrict__ hin, float* __restrict__ hout,   // FINAL: hout = cross-accumulator (zeroed)
    const float* __restrict__ RT, const float* __restrict__ AR, const float* __restrict__ AQ,
    const float* __restrict__ w1, const float* __restrict__ w2, const float* __restrict__ W3,
    int E, int nrel, int ntime,
    const int* __restrict__ ndst, int* __restrict__ ncnt, int* __restrict__ nrank, int nE,
    const float* __restrict__ wcls, const float* __restrict__ bcls,
    const int* __restrict__ nbv, const int* __restrict__ nev, const int* __restrict__ nentp,
    float* __restrict__ outp, int* __restrict__ list, int* __restrict__ listc)
{
  int lb;
  if (HIST){
    int g=blockIdx.x;
    int r=g%3, b3=g/3;
    if (r==2){                           // histogram role (next layer), no LDS, latency-bound
      int H=gridDim.x/3;
      int stride=H*256;
      for (int e=b3*256+threadIdx.x; e<nE; e+=stride)
        nrank[e]=atomicAdd(&ncnt[ndst[e]],1);
      return;
    }
    lb=b3*2+r;
  } else lb=blockIdx.x;
  int bstart=lb*256;
  if (bstart>=E) return;

  __shared__ float sW1h[HID*DD];
  __shared__ float sW2[32];
  __shared__ float sW3[3*DD*DD];
  __shared__ float smsg[256*MROW];
  __shared__ int   sdst[256];
  __shared__ int   s_prevdst, s_nextdst;
  if (HASH){
    for (int t=threadIdx.x; t<HID*DD; t+=blockDim.x){ int j=t/DD,k=t-j*DD; sW1h[t]=w1[j*3*DD+k]; }
    for (int t=threadIdx.x; t<3*DD*DD; t+=blockDim.x) sW3[t]=W3[t];
  }
  if (threadIdx.x<HID) sW2[threadIdx.x]=w2[threadIdx.x];

  int tid = threadIdx.x;
  int bsize = E - bstart; if (bsize>256) bsize=256;
  int j = bstart + tid;
  bool active = (tid < bsize);

  if (tid==0){
    s_prevdst = (bstart>0) ? recs[-1 + (ptrdiff_t)bstart].w : -1;
    s_nextdst = (bstart+bsize < E) ? recs[bstart+bsize].w : -1;
  }
  __syncthreads();   // weights + s_prev/s_next visible

  int dstv = -1;
  float m[DD];
  if (active){
    int4 rc = recs[j];
    int s = rc.x;
    int r = rc.y & 0xFFFF;
    int q = ((unsigned)rc.y) >> 16;
    int t = rc.z;
    dstv  = rc.w;
    int sel = (t>0)?2:((t==0)?1:0);
    int ta = (t<0)?-t:t;

    float h[DD];
    if (HASH){
      load20(hin+(size_t)s*DD, h);
#pragma unroll
      for (int i=0;i<DD;i++) h[i]=fmaxf(h[i],0.01f*h[i]);   // leaky folded into gather
    }

    float a[HID];
    {
      const float4* ap=(const float4*)(AR+(size_t)r*32);
      const float4* qp=(const float4*)(AQ+(size_t)q*32);
#pragma unroll
      for (int c=0;c<7;c++){
        float4 x=ap[c], y=qp[c];
        a[4*c+0]=x.x+y.x; a[4*c+1]=x.y+y.y; a[4*c+2]=x.z+y.z; a[4*c+3]=x.w+y.w;
      }
      float2 x=*(const float2*)(AR+(size_t)r*32+28);
      float2 y=*(const float2*)(AQ+(size_t)q*32+28);
      a[28]=x.x+y.x; a[29]=x.y+y.y;
    }
    if (HASH){
#pragma unroll
      for (int jj=0;jj<HID;jj++){
        const float4* wr=(const float4*)&sW1h[jj*DD];
        float sum=a[jj];
#pragma unroll
        for (int c=0;c<5;c++){ float4 w=wr[c]; sum += h[4*c]*w.x+h[4*c+1]*w.y+h[4*c+2]*w.z+h[4*c+3]*w.w; }
        a[jj]=sum;
      }
    }
    float z=0.f;
#pragma unroll
    for (int jj=0;jj<HID;jj++) z += fmaxf(a[jj],0.f)*sW2[jj];
    float score = 1.f/(1.f+__expf(-z));

    float tr[DD];
    load20(RT + ((size_t)(sel*nrel+r)*ntime + ta)*DD, tr);
    if (HASH){
      const float* Ws = sW3 + sel*DD*DD;
#pragma unroll
      for (int i=0;i<DD;i++){
        const float4* wr=(const float4*)(Ws+i*DD);
        float sum=tr[i];
#pragma unroll
        for (int c=0;c<5;c++){ float4 w=wr[c]; sum += h[4*c]*w.x+h[4*c+1]*w.y+h[4*c+2]*w.z+h[4*c+3]*w.w; }
        tr[i]=sum;
      }
    }
#pragma unroll
    for (int i=0;i<DD;i++){ m[i]=score*tr[i]; smsg[tid*MROW+i]=m[i]; }
  }
  sdst[tid] = active ? dstv : -2;
  __syncthreads();

  if (!active) return;
  bool isHead = (tid==0) ? (s_prevdst != dstv) : (sdst[tid-1] != dstv);
  if (!(isHead || tid==0)) return;
  int k=tid+1;
  for (; k<bsize && sdst[k]==dstv; ++k){
    const float* row=&smsg[k*MROW];
#pragma unroll
    for (int i=0;i<DD;i++) m[i]+=row[i];
  }
  bool crossStart = (tid==0 && !isHead);
  bool crossEnd   = (k==bsize) && (s_nextdst==dstv);
  if (crossStart || crossEnd){
    float* o = hout + (size_t)dstv*DD;
#pragma unroll
    for (int i=0;i<DD;i++) atomicAdd(o+i, m[i]);
    if (FINAL && isHead){                 // true head of a crossing segment: defer to sparse pass
      int p = atomicAdd(listc,1);
      list[p] = dstv;
    }
  } else {
    if (!FINAL){
      float4* op=(float4*)(hout + (size_t)dstv*DD);
#pragma unroll
      for (int c=0;c<5;c++){ float4 v; v.x=m[4*c]; v.y=m[4*c+1]; v.z=m[4*c+2]; v.w=m[4*c+3]; op[c]=v; }
    } else {
      float rsum=bcls[0];
#pragma unroll
      for (int i=0;i<DD;i++){ float x=fmaxf(m[i],0.01f*m[i]); rsum += x*wcls[i]; }
      long long stride = nentp[0];
      outp[(long long)nbv[dstv]*stride + nev[dstv]] = rsum;
    }
  }
}

// finish the (rare) cross-block segments of layer 2
__global__ void __launch_bounds__(256) k_fsparse(const float* __restrict__ buf,
   const float* __restrict__ wcls,const float* __restrict__ bcls,
   const int* __restrict__ nb,const int* __restrict__ ne,const int* __restrict__ nentp,
   float* __restrict__ out,const int* __restrict__ list,const int* __restrict__ listc){
  int c=*listc;
  int i=blockIdx.x*blockDim.x+threadIdx.x;
  if (i>=c) return;
  int n=list[i];
  float rsum=bcls[0];
  const float* h=buf+(size_t)n*DD;
#pragma unroll
  for (int jj=0;jj<DD;jj++){ float v=h[jj]; float x=fmaxf(v,0.01f*v); rsum+=x*wcls[jj]; }
  long long stride=nentp[0];
  out[(long long)nb[n]*stride+ne[n]]=rsum;
}

// ================= fallback (round-2 proven atomic path) =================
template<bool HASH>
__global__ void __launch_bounds__(256) k_edge(
    const int* __restrict__ src, const int* __restrict__ dst,
    const int* __restrict__ rel, const int* __restrict__ qrel,
    const int* __restrict__ rtm,
    const float* __restrict__ hin, float* __restrict__ hout,
    const float* __restrict__ RT, const float* __restrict__ AR, const float* __restrict__ AQ,
    const float* __restrict__ w1, const float* __restrict__ w2, const float* __restrict__ W3,
    int E, int nrel, int ntime)
{
  __shared__ float sW1h[HID*DD];
  __shared__ float sW2[32];
  __shared__ float sW3[3*DD*DD];
  for (int t=threadIdx.x; t<HID*DD; t+=blockDim.x){ int j=t/DD,k=t-j*DD; sW1h[t]=w1[j*3*DD+k]; }
  if (threadIdx.x<HID) sW2[threadIdx.x]=w2[threadIdx.x];
  for (int t=threadIdx.x; t<3*DD*DD; t+=blockDim.x) sW3[t]=W3[t];
  __syncthreads();
  int e = blockIdx.x*blockDim.x+threadIdx.x;
  if (e>=E) return;
  int s=src[e], d=dst[e], r=rel[e], q=qrel[e], t=rtm[e];
  int sel = (t>0)?2:((t==0)?1:0);
  int ta = (t<0)?-t:t;
  float h[DD];
  if (HASH){
    load20(hin+(size_t)s*DD, h);
#pragma unroll
    for (int i=0;i<DD;i++) h[i]=fmaxf(h[i],0.01f*h[i]);
  }
  float a[HID];
  {
    const float4* ap=(const float4*)(AR+(size_t)r*32);
    const float4* qp=(const float4*)(AQ+(size_t)q*32);
#pragma unroll
    for (int c=0;c<7;c++){
      float4 x=ap[c], y=qp[c];
      a[4*c+0]=x.x+y.x; a[4*c+1]=x.y+y.y; a[4*c+2]=x.z+y.z; a[4*c+3]=x.w+y.w;
    }
    float2 x=*(const float2*)(AR+(size_t)r*32+28);
    float2 y=*(const float2*)(AQ+(size_t)q*32+28);
    a[28]=x.x+y.x; a[29]=x.y+y.y;
  }
  if (HASH){
#pragma unroll
    for (int j=0;j<HID;j++){
      const float4* wr=(const float4*)&sW1h[j*DD];
      float sum=a[j];
#pragma unroll
      for (int c=0;c<5;c++){ float4 w=wr[c]; sum += h[4*c]*w.x+h[4*c+1]*w.y+h[4*c+2]*w.z+h[4*c+3]*w.w; }
      a[j]=sum;
    }
  }
  float z=0.f;
#pragma unroll
  for (int j=0;j<HID;j++) z += fmaxf(a[j],0.f)*sW2[j];
  float score = 1.f/(1.f+__expf(-z));
  float tr[DD];
  load20(RT + ((size_t)(sel*nrel+r)*ntime + ta)*DD, tr);
  if (HASH){
    const float* Ws = sW3 + sel*DD*DD;
#pragma unroll
    for (int i=0;i<DD;i++){
      const float4* wr=(const float4*)(Ws+i*DD);
      float sum=tr[i];
#pragma unroll
      for (int c=0;c<5;c++){ float4 w=wr[c]; sum += h[4*c]*w.x+h[4*c+1]*w.y+h[4*c+2]*w.z+h[4*c+3]*w.w; }
      tr[i]=sum;
    }
  }
  float* o = hout + (size_t)d*DD;
#pragma unroll
  for (int i=0;i<DD;i++) atomicAdd(o+i, score*tr[i]);
}

__global__ void k_result(const float* __restrict__ h, const float* __restrict__ wcls,
                         const float* __restrict__ bcls, float* __restrict__ res, int N){
  int i = blockIdx.x*blockDim.x+threadIdx.x;
  if (i>=N) return;
  float acc = bcls[0];
  const float4* q=(const float4*)(h+(size_t)i*DD);
#pragma unroll
  for (int c=0;c<5;c++){
    float4 v=q[c];
    float x0=fmaxf(v.x,0.01f*v.x), x1=fmaxf(v.y,0.01f*v.y);
    float x2=fmaxf(v.z,0.01f*v.z), x3=fmaxf(v.w,0.01f*v.w);
    acc += x0*wcls[4*c]+x1*wcls[4*c+1]+x2*wcls[4*c+2]+x3*wcls[4*c+3];
  }
  res[i]=acc;
}

__global__ void k_scatter(const float* __restrict__ res, const int* __restrict__ nb,
                          const int* __restrict__ ne, const int* __restrict__ nentp,
                          float* __restrict__ out, int N){
  int i=blockIdx.x*blockDim.x+threadIdx.x;
  if (i>=N) return;
  long long stride = nentp[0];
  out[(long long)nb[i]*stride + ne[i]] = res[i];
}

extern "C" void kernel_launch(void* const* d_in, const int* in_sizes, int n_in,
                              void* d_out, int out_size, void* d_ws, size_t ws_size,
                              hipStream_t stream){
  const int*   src =(const int*)d_in[0];
  const int*   dst =(const int*)d_in[1];
  const int*   rel =(const int*)d_in[2];
  const int*   qrel=(const int*)d_in[3];
  const int*   rtm =(const int*)d_in[4];
  const int*   nb  =(const int*)d_in[5];
  const int*   ne  =(const int*)d_in[6];
  const float* rela=(const float*)d_in[7];
  const float* timee=(const float*)d_in[8];
  const float* w1  =(const float*)d_in[9];
  const float* w2  =(const float*)d_in[10];
  const float* wp  =(const float*)d_in[11];
  const float* wn  =(const float*)d_in[12];
  const float* wf  =(const float*)d_in[13];
  const float* wcls=(const float*)d_in[14];
  const float* bcls=(const float*)d_in[15];
  const int*   nentp=(const int*)d_in[17];

  const int Lc=3;
  int LE=in_sizes[0]; int E=LE/Lc;
  int N=in_sizes[5];
  int nrel=in_sizes[7]/DD;
  int ntime=in_sizes[8]/DD;

  auto al=[](size_t x){ return (x+(size_t)255)&~(size_t)255; };
  size_t szBuf =al((size_t)N*DD*4);
  size_t szRT  =al((size_t)3*nrel*ntime*DD*4);
  size_t szA   =al((size_t)nrel*32*4);
  size_t szW3  =al((size_t)3*DD*DD*4);
  size_t szRow =al((size_t)Lc*((size_t)N+1)*4);
  size_t szRank=al((size_t)LE*4);
  size_t szCnt =al((size_t)Lc*N*4);
  size_t szRecs=al((size_t)LE*16);
  size_t szPart=al((size_t)NB_SCAN*4);
  size_t szList=al((size_t)(8192+16)*4);
  size_t need = 2*szBuf+szRT+2*szA+szW3+szRow+szRank+szCnt+szRecs+szPart+szList;

  dim3 blk(256);
  int prepTot = (3*DD*DD > nrel*HID) ? 3*DD*DD : nrel*HID;
  int rtTot=3*nrel*ntime;

  if (ws_size >= need){
    char* base=(char*)d_ws;
    size_t off=0;
    float* buf0=(float*)(base+off); off+=szBuf;
    float* buf1=(float*)(base+off); off+=szBuf;
    float* RT  =(float*)(base+off); off+=szRT;
    float* AR  =(float*)(base+off); off+=szA;
    float* AQ  =(float*)(base+off); off+=szA;
    float* W3  =(float*)(base+off); off+=szW3;
    int*   rowptr=(int*)(base+off); off+=szRow;     // Lc*(N+1)
    int*   rank=(int*)(base+off);  off+=szRank;
    int*   cnt =(int*)(base+off);  off+=szCnt;      // Lc*N
    int4*  recs=(int4*)(base+off); off+=szRecs;
    int*   part=(int*)(base+off);  off+=szPart;
    int*   listc=(int*)(base+off);
    int*   list =listc+16;          off+=szList;

    float* dout=(float*)d_out;

    (void)hipMemsetAsync(cnt,0,(size_t)Lc*N*4,stream);
    k_prep<<<dim3((prepTot+255)/256),blk,0,stream>>>(rela,w1,wp,wn,wf,W3,AR,AQ,nrel);
    k_rt<<<dim3((rtTot+255)/256),blk,0,stream>>>(rela,timee,W3,RT,nrel,ntime);

    // F0: zero d_out+buf0+buf1 (even blocks) || hist layer0 (odd blocks)
    size_t nd4=(size_t)out_size>>2;        // out_size divisible by 4
    size_t nb4=(size_t)N*DD/4;
    k_pre<<<dim3(8192),blk,0,stream>>>(dst,cnt,rank,E,(float4*)dout,nd4,(float4*)buf0,(float4*)buf1,nb4);

    int C=(N+NB_SCAN-1)/NB_SCAN;
    int LB=(E+255)/256;
    int H=(LB+1)/2;

    for (int l=0;l<Lc;++l){
      int* cnt_l = cnt + (size_t)l*N;
      int* row_l = rowptr + (size_t)l*(N+1);
      // scan
      k_scan_part<<<dim3(NB_SCAN),blk,0,stream>>>(cnt_l,part,N,C);
      k_scan_top<<<dim3(1),dim3(NB_SCAN),0,stream>>>(part);
      k_scan_write<<<dim3(NB_SCAN),blk,0,stream>>>(cnt_l,part,row_l,N,C);
      // scatter (+extras: l0 fills b_cls into all node slots; l2 zeroes buf0 + list counter)
      size_t eo=(size_t)l*E;
      int xb = (l==0)?1024:((l==2)?2048:0);
      int mode=(l==0)?0:2;
      k_scat<<<dim3(xb+LB),blk,0,stream>>>(src+eo,dst+eo,rel+eo,qrel+eo,rtm+eo,
          rank+eo,row_l,recs+eo,E,xb,mode,
          dout,nb,ne,nentp,bcls,N,(float4*)buf0,nb4,listc);
      // fused layer (+hist of next layer for l<2)
      if (l==0){
        k_fused<false,true,false><<<dim3(3*H),blk,0,stream>>>(recs,nullptr,buf0,
            RT,AR,AQ,w1,w2,W3,E,nrel,ntime,
            dst+(size_t)E,cnt+(size_t)N,rank+(size_t)E,E,
            nullptr,nullptr,nullptr,nullptr,nullptr,nullptr,nullptr,nullptr);
      } else if (l==1){
        k_fused<true,true,false><<<dim3(3*H),blk,0,stream>>>(recs+(size_t)E,buf0,buf1,
            RT,AR,AQ,w1,w2,W3,E,nrel,ntime,
            dst+(size_t)2*E,cnt+(size_t)2*N,rank+(size_t)2*E,E,
            nullptr,nullptr,nullptr,nullptr,nullptr,nullptr,nullptr,nullptr);
      } else {
        k_fused<true,false,true><<<dim3(LB),blk,0,stream>>>(recs+(size_t)2*E,buf1,buf0,
            RT,AR,AQ,w1,w2,W3,E,nrel,ntime,
            nullptr,nullptr,nullptr,0,
            wcls,bcls,nb,ne,nentp,dout,list,listc);
      }
    }
    k_fsparse<<<dim3(32),blk,0,stream>>>(buf0,wcls,bcls,nb,ne,nentp,dout,list,listc);
  } else {
    // fallback: proven round-2 atomic path (scratch carved from d_out, res in ws)
    char* base=(char*)d_out; float* res=(float*)d_ws;
    size_t off=0;
    float* buf0=(float*)(base+off); off+=szBuf;
    float* buf1=(float*)(base+off); off+=szBuf;
    float* RT  =(float*)(base+off); off+=szRT;
    float* AR  =(float*)(base+off); off+=szA;
    float* AQ  =(float*)(base+off); off+=szA;
    float* W3  =(float*)(base+off); off+=szW3;
    k_prep<<<dim3((prepTot+255)/256),blk,0,stream>>>(rela,w1,wp,wn,wf,W3,AR,AQ,nrel);
    k_rt<<<dim3((rtTot+255)/256),blk,0,stream>>>(rela,timee,W3,RT,nrel,ntime);
    dim3 egrid((E+255)/256);
    dim3 ngrid((N+255)/256);
    (void)hipMemsetAsync(buf0,0,(size_t)N*DD*4,stream);
    k_edge<false><<<egrid,blk,0,stream>>>(src,dst,rel,qrel,rtm,nullptr,buf0,RT,AR,AQ,w1,w2,W3,E,nrel,ntime);
    (void)hipMemsetAsync(buf1,0,(size_t)N*DD*4,stream);
    k_edge<true><<<egrid,blk,0,stream>>>(src+(size_t)E,dst+(size_t)E,rel+(size_t)E,qrel+(size_t)E,rtm+(size_t)E,
                                         buf0,buf1,RT,AR,AQ,w1,w2,W3,E,nrel,ntime);
    (void)hipMemsetAsync(buf0,0,(size_t)N*DD*4,stream);
    k_edge<true><<<egrid,blk,0,stream>>>(src+(size_t)2*E,dst+(size_t)2*E,rel+(size_t)2*E,qrel+(size_t)2*E,rtm+(size_t)2*E,
                                         buf1,buf0,RT,AR,AQ,w1,w2,W3,E,nrel,ntime);
    k_result<<<ngrid,blk,0,stream>>>(buf0,wcls,bcls,res,N);
    (void)hipMemsetAsync(d_out,0,(size_t)out_size*sizeof(float),stream);
    k_scatter<<<ngrid,blk,0,stream>>>(res,nb,ne,nentp,(float*)d_out,N);
  }
}